// Round 6
// baseline (254.203 us; speedup 1.0000x reference)
//
#include <hip/hip_runtime.h>
#include <math.h>

#define EPSV 1e-5f

// conv1 (3-tap, zero-pad) + relu at the 3 positions of one sample
__device__ __forceinline__ void conv3_relu(float x0, float x1, float x2,
                                           float wa, float wb, float wc, float bb,
                                           float& t0, float& t1, float& t2)
{
    t0 = fmaxf(fmaf(wb, x0, fmaf(wc, x1, bb)), 0.f);
    t1 = fmaxf(fmaf(wa, x0, fmaf(wb, x1, fmaf(wc, x2, bb))), 0.f);
    t2 = fmaxf(fmaf(wa, x1, fmaf(wb, x2, bb)), 0.f);
}

// ---------------------------------------------------------------------------
// Pass 1: per-channel sum/sumsq of relu(conv1(x)+b1), 16 channels.
// R5-k_final recipe: LDS-broadcast weights, 4 samples/lane via float4,
// per-lane cur[32] accumulators, xor-tree tail (R3-proven).
// partials[block*32 + v]: v<16 sum, v>=16 sq
// ---------------------------------------------------------------------------
__global__ __launch_bounds__(256) void k_stats1(const float* __restrict__ x,
                                                const float* __restrict__ w1,
                                                const float* __restrict__ b1,
                                                float* __restrict__ partials,
                                                int B)
{
    __shared__ float4 sW1[16];
    int t = threadIdx.x;
    if (t < 16) sW1[t] = make_float4(w1[3*t], w1[3*t+1], w1[3*t+2], b1[t]);
    __syncthreads();

    float cur[32];   // [0,16): sum, [16,32): sq
#pragma unroll
    for (int i = 0; i < 32; ++i) cur[i] = 0.f;

    int nchunk = (B + 3) >> 2;
    for (int ch = blockIdx.x * 256 + t; ch < nchunk; ch += gridDim.x * 256) {
        int s0 = ch << 2;
        float X[4][3];
        if (s0 + 4 <= B) {
            const float4* xp = (const float4*)(x + (size_t)s0 * 3);
            float4 A = xp[0], Bq = xp[1], Cq = xp[2];
            X[0][0]=A.x;  X[0][1]=A.y;  X[0][2]=A.z;
            X[1][0]=A.w;  X[1][1]=Bq.x; X[1][2]=Bq.y;
            X[2][0]=Bq.z; X[2][1]=Bq.w; X[2][2]=Cq.x;
            X[3][0]=Cq.y; X[3][1]=Cq.z; X[3][2]=Cq.w;
        } else {
#pragma unroll
            for (int m = 0; m < 4; ++m) {
                int s = s0 + m;
                if (s < B) { X[m][0]=x[3*s]; X[m][1]=x[3*s+1]; X[m][2]=x[3*s+2]; }
                else { X[m][0]=X[m][1]=X[m][2]=0.f; }
            }
        }
#pragma unroll 4
        for (int g = 0; g < 16; ++g) {
            float4 w = sW1[g];
#pragma unroll
            for (int m = 0; m < 4; ++m) {
                if (s0 + m < B) {
                    float t0, t1, t2;
                    conv3_relu(X[m][0], X[m][1], X[m][2], w.x, w.y, w.z, w.w, t0, t1, t2);
                    cur[g]      += t0 + t1 + t2;
                    cur[16 + g]  = fmaf(t0, t0, fmaf(t1, t1, fmaf(t2, t2, cur[16 + g])));
                }
            }
        }
    }

    // xor-tree: lane (L&31) ends holding total of slot (L&31)  [R3-proven]
    int lane = t & 63, wid = t >> 6;
#pragma unroll
    for (int i = 0; i < 32; ++i) cur[i] += __shfl_xor(cur[i], 32, 64);
#pragma unroll
    for (int half = 16; half >= 1; half >>= 1) {
#pragma unroll
        for (int i = 0; i < half; ++i) {
            bool up = (lane & half);
            float keep = up ? cur[i + half] : cur[i];
            float send = up ? cur[i] : cur[i + half];
            cur[i] = keep + __shfl_xor(send, half, 64);
        }
    }
    __shared__ float red[4][32];
    if (lane < 32) red[wid][lane] = cur[0];
    __syncthreads();
    if (t < 32)
        partials[blockIdx.x * 32 + t] = red[0][t] + red[1][t] + red[2][t] + red[3][t];
}

// ---------------------------------------------------------------------------
// Finalize 1: BN1 scale/shift, fold into conv2 weights (padding-aware bias).
// ---------------------------------------------------------------------------
__global__ __launch_bounds__(256) void k_fin1(const float* __restrict__ partials,
                                              const float* __restrict__ g1,
                                              const float* __restrict__ bt1,
                                              const float* __restrict__ w2,
                                              const float* __restrict__ b2,
                                              float* __restrict__ w2f,
                                              float* __restrict__ b2f,
                                              float Ninv, int nb)
{
    __shared__ float4 red4[32][8];
    __shared__ float tot[32];
    __shared__ float ssc[16], ssh[16];
    int t = threadIdx.x;
    {
        int v4 = t & 7, c = t >> 3;
        float4 a = make_float4(0.f, 0.f, 0.f, 0.f);
        for (int b = c; b < nb; b += 32) {
            float4 p = ((const float4*)partials)[b * 8 + v4];
            a.x += p.x; a.y += p.y; a.z += p.z; a.w += p.w;
        }
        red4[c][v4] = a;
    }
    __syncthreads();
    if (t < 8) {
        float4 a = make_float4(0.f, 0.f, 0.f, 0.f);
#pragma unroll
        for (int c = 0; c < 32; ++c) {
            float4 p = red4[c][t];
            a.x += p.x; a.y += p.y; a.z += p.z; a.w += p.w;
        }
        tot[4*t+0] = a.x; tot[4*t+1] = a.y; tot[4*t+2] = a.z; tot[4*t+3] = a.w;
    }
    __syncthreads();
    if (t < 16) {
        float mean = tot[t] * Ninv;
        float var  = fmaxf(tot[16 + t] * Ninv - mean * mean, 0.f);
        float rstd = rsqrtf(var + EPSV);
        float sc = g1[t] * rstd;
        ssc[t] = sc;
        ssh[t] = bt1[t] - mean * sc;
    }
    __syncthreads();
    if (t < 96) {
        int o = t / 3, p = t % 3;
        int g = o >> 1;
        w2f[t] = w2[t] * ssc[g];
        float wv0 = w2[3*o], wv1 = w2[3*o+1], wv2 = w2[3*o+2];
        float sv = (p == 0) ? (wv1 + wv2) : ((p == 1) ? (wv0 + wv1 + wv2) : (wv0 + wv1));
        b2f[t] = b2[o] + ssh[g] * sv;
    }
}

// ---------------------------------------------------------------------------
// Pass 2: per-channel sum/sumsq of relu(conv2(bn1(relu1))), 32 channels.
// R5-k_final recipe: LDS-broadcast weights, 4 samples/lane via float4,
// per-lane cur[64], xor-tree tail (R3-proven). No cross-lane redundancy.
// partials[block*64 + v]: v<32 sum, v>=32 sq
// ---------------------------------------------------------------------------
__global__ __launch_bounds__(256) void k_stats2(const float* __restrict__ x,
                                                const float* __restrict__ w1,
                                                const float* __restrict__ b1,
                                                const float* __restrict__ w2f,
                                                const float* __restrict__ b2f,
                                                float* __restrict__ partials,
                                                int B)
{
    __shared__ float4 sW1[16];
    __shared__ float4 sU[32];   // ua,ub,uc,c0
    __shared__ float2 sC[32];   // c1,c2
    int t = threadIdx.x;
    if (t < 16) sW1[t] = make_float4(w1[3*t], w1[3*t+1], w1[3*t+2], b1[t]);
    else if (t >= 32 && t < 64) {
        int o = t - 32;
        sU[o] = make_float4(w2f[3*o], w2f[3*o+1], w2f[3*o+2], b2f[3*o]);
        sC[o] = make_float2(b2f[3*o+1], b2f[3*o+2]);
    }
    __syncthreads();

    float cur[64];  // [0,32): sum, [32,64): sq
#pragma unroll
    for (int i = 0; i < 64; ++i) cur[i] = 0.f;

    int nchunk = (B + 3) >> 2;
    for (int ch = blockIdx.x * 256 + t; ch < nchunk; ch += gridDim.x * 256) {
        int s0 = ch << 2;
        float X[4][3];
        if (s0 + 4 <= B) {
            const float4* xp = (const float4*)(x + (size_t)s0 * 3);
            float4 A = xp[0], Bq = xp[1], Cq = xp[2];
            X[0][0]=A.x;  X[0][1]=A.y;  X[0][2]=A.z;
            X[1][0]=A.w;  X[1][1]=Bq.x; X[1][2]=Bq.y;
            X[2][0]=Bq.z; X[2][1]=Bq.w; X[2][2]=Cq.x;
            X[3][0]=Cq.y; X[3][1]=Cq.z; X[3][2]=Cq.w;
        } else {
#pragma unroll
            for (int m = 0; m < 4; ++m) {
                int s = s0 + m;
                if (s < B) { X[m][0]=x[3*s]; X[m][1]=x[3*s+1]; X[m][2]=x[3*s+2]; }
                else { X[m][0]=X[m][1]=X[m][2]=0.f; }
            }
        }
#pragma unroll 4
        for (int g = 0; g < 16; ++g) {
            float4 w = sW1[g];
            float r[4][3];
#pragma unroll
            for (int m = 0; m < 4; ++m)
                conv3_relu(X[m][0], X[m][1], X[m][2], w.x, w.y, w.z, w.w,
                           r[m][0], r[m][1], r[m][2]);
#pragma unroll
            for (int jj = 0; jj < 2; ++jj) {
                int o = 2 * g + jj;
                float4 u = sU[o];
                float2 cc = sC[o];
#pragma unroll
                for (int m = 0; m < 4; ++m) {
                    if (s0 + m < B) {
                        float v0 = fmaxf(fmaf(u.y, r[m][0], fmaf(u.z, r[m][1], u.w)), 0.f);
                        float v1 = fmaxf(fmaf(u.x, r[m][0], fmaf(u.y, r[m][1], fmaf(u.z, r[m][2], cc.x))), 0.f);
                        float v2 = fmaxf(fmaf(u.x, r[m][1], fmaf(u.y, r[m][2], cc.y)), 0.f);
                        cur[o]      += v0 + v1 + v2;
                        cur[32 + o]  = fmaf(v0, v0, fmaf(v1, v1, fmaf(v2, v2, cur[32 + o])));
                    }
                }
            }
        }
    }

    // xor-tree over 64 slots: lane L ends holding total of slot L  [R3-proven]
    int lane = t & 63, wid = t >> 6;
#pragma unroll
    for (int half = 32; half >= 1; half >>= 1) {
#pragma unroll
        for (int i = 0; i < half; ++i) {
            bool up = (lane & half);
            float keep = up ? cur[i + half] : cur[i];
            float send = up ? cur[i] : cur[i + half];
            cur[i] = keep + __shfl_xor(send, half, 64);
        }
    }
    __shared__ float red[4][64];
    red[wid][lane] = cur[0];
    __syncthreads();
    if (t < 64)
        partials[blockIdx.x * 64 + t] = red[0][t] + red[1][t] + red[2][t] + red[3][t];
}

// ---------------------------------------------------------------------------
// Finalize 2: BN2 scale/shift; fold BN2 + mean(1/3) into fc1, TRANSPOSED:
// fw1sT[o*16 + j] = fw1[j*32+o] * ssc[o] / 3  (k_final reads per-channel rows)
// c1[j] = fb1[j] + sum_c fw1[j*32+c] * ssh[c]
// ---------------------------------------------------------------------------
__global__ __launch_bounds__(256) void k_fin2(const float* __restrict__ partials,
                                              const float* __restrict__ g2,
                                              const float* __restrict__ bt2,
                                              const float* __restrict__ fw1,
                                              const float* __restrict__ fb1,
                                              float* __restrict__ fw1sT,
                                              float* __restrict__ c1,
                                              float Ninv, int nb)
{
    __shared__ float4 red4[16][16];
    __shared__ float tot[64];
    __shared__ float ssc[32], ssh[32];
    int t = threadIdx.x;
    {
        int v4 = t & 15, c = t >> 4;
        float4 a = make_float4(0.f, 0.f, 0.f, 0.f);
        for (int b = c; b < nb; b += 16) {
            float4 p = ((const float4*)partials)[b * 16 + v4];
            a.x += p.x; a.y += p.y; a.z += p.z; a.w += p.w;
        }
        red4[c][v4] = a;
    }
    __syncthreads();
    if (t < 16) {
        float4 a = make_float4(0.f, 0.f, 0.f, 0.f);
#pragma unroll
        for (int c = 0; c < 16; ++c) {
            float4 p = red4[c][t];
            a.x += p.x; a.y += p.y; a.z += p.z; a.w += p.w;
        }
        tot[4*t+0] = a.x; tot[4*t+1] = a.y; tot[4*t+2] = a.z; tot[4*t+3] = a.w;
    }
    __syncthreads();
    if (t < 32) {
        float mean = tot[t] * Ninv;
        float var  = fmaxf(tot[32 + t] * Ninv - mean * mean, 0.f);
        float rstd = rsqrtf(var + EPSV);
        float sc = g2[t] * rstd;
        ssc[t] = sc;
        ssh[t] = bt2[t] - mean * sc;
    }
    __syncthreads();
    for (int idx = t; idx < 512; idx += 256) {
        int o = idx >> 4, j = idx & 15;
        fw1sT[idx] = fw1[j * 32 + o] * ssc[o] * (1.0f / 3.0f);
    }
    if (t < 16) {
        float a = fb1[t];
#pragma unroll
        for (int c = 0; c < 32; ++c) a = fmaf(fw1[t * 32 + c], ssh[c], a);
        c1[t] = a;
    }
}

// ---------------------------------------------------------------------------
// Pass 3 (R5-proven): full forward, one sample per lane, fc1 fused into the
// conv loop; persistent state = acc[16]+x only. Grid 2048 -> 2 samples/lane
// to amortize LDS staging.
// ---------------------------------------------------------------------------
__global__ __launch_bounds__(256) void k_final(const float* __restrict__ x,
                                               const float* __restrict__ w1,
                                               const float* __restrict__ b1,
                                               const float* __restrict__ w2f,
                                               const float* __restrict__ b2f,
                                               const float* __restrict__ fw1sT,
                                               const float* __restrict__ c1,
                                               const float* __restrict__ fw2,
                                               const float* __restrict__ fb2,
                                               float* __restrict__ out,
                                               int B)
{
    __shared__ float4 sW1[16];   // conv1 w + b
    __shared__ float4 sU[32];    // conv2 w + bias(pos0)
    __shared__ float2 sC[32];    // bias(pos1), bias(pos2)
    __shared__ float4 sFT[128];  // sFT[o*4+k] = fw1sT[o*16+4k .. +3]
    __shared__ float2 sJ[16];    // (c1[j], fw2[j])
    __shared__ float  sb2;
    int t = threadIdx.x;
    if (t < 16) sW1[t] = make_float4(w1[3*t], w1[3*t+1], w1[3*t+2], b1[t]);
    else if (t >= 32 && t < 64) {
        int o = t - 32;
        sU[o] = make_float4(w2f[3*o], w2f[3*o+1], w2f[3*o+2], b2f[3*o]);
        sC[o] = make_float2(b2f[3*o+1], b2f[3*o+2]);
    } else if (t >= 64 && t < 192) {
        sFT[t - 64] = ((const float4*)fw1sT)[t - 64];
    } else if (t >= 192 && t < 208) {
        sJ[t - 192] = make_float2(c1[t - 192], fw2[t - 192]);
    } else if (t == 224) {
        sb2 = fb2[0];
    }
    __syncthreads();

    for (int s = blockIdx.x * 256 + t; s < B; s += gridDim.x * 256) {
        float x0 = x[3*s], x1 = x[3*s+1], x2 = x[3*s+2];

        float acc[16];
#pragma unroll
        for (int j = 0; j < 16; ++j) acc[j] = 0.f;

#pragma unroll 4
        for (int g = 0; g < 16; ++g) {
            float4 w = sW1[g];
            float r0, r1, r2;
            conv3_relu(x0, x1, x2, w.x, w.y, w.z, w.w, r0, r1, r2);
#pragma unroll
            for (int jj = 0; jj < 2; ++jj) {
                int o = 2 * g + jj;
                float4 u = sU[o];
                float2 cc = sC[o];
                float v0 = fmaxf(fmaf(u.y, r0, fmaf(u.z, r1, u.w)), 0.f);
                float v1 = fmaxf(fmaf(u.x, r0, fmaf(u.y, r1, fmaf(u.z, r2, cc.x))), 0.f);
                float v2 = fmaxf(fmaf(u.x, r1, fmaf(u.y, r2, cc.y)), 0.f);
                float so = v0 + v1 + v2;
#pragma unroll
                for (int k = 0; k < 4; ++k) {
                    float4 f = sFT[o * 4 + k];
                    acc[4*k+0] = fmaf(f.x, so, acc[4*k+0]);
                    acc[4*k+1] = fmaf(f.y, so, acc[4*k+1]);
                    acc[4*k+2] = fmaf(f.z, so, acc[4*k+2]);
                    acc[4*k+3] = fmaf(f.w, so, acc[4*k+3]);
                }
            }
        }

        float r = sb2;
#pragma unroll
        for (int j = 0; j < 16; ++j) {
            float2 jw = sJ[j];
            r = fmaf(jw.y, fmaxf(acc[j] + jw.x, 0.f), r);
        }
        out[s] = r;
    }
}

// ---------------------------------------------------------------------------
extern "C" void kernel_launch(void* const* d_in, const int* in_sizes, int n_in,
                              void* d_out, int out_size, void* d_ws, size_t ws_size,
                              hipStream_t stream)
{
    const float* x   = (const float*)d_in[0];
    const float* w1  = (const float*)d_in[1];
    const float* b1  = (const float*)d_in[2];
    const float* g1  = (const float*)d_in[3];
    const float* bt1 = (const float*)d_in[4];
    const float* w2  = (const float*)d_in[5];
    const float* b2  = (const float*)d_in[6];
    const float* g2  = (const float*)d_in[7];
    const float* bt2 = (const float*)d_in[8];
    const float* fw1 = (const float*)d_in[9];
    const float* fb1 = (const float*)d_in[10];
    const float* fw2 = (const float*)d_in[11];
    const float* fb2 = (const float*)d_in[12];

    int B = in_sizes[0] / 3;

    int nb1 = 1024, nb2 = 1024;
    while ((size_t)(nb1 * 32 + nb2 * 64 + 720) * sizeof(float) > ws_size && nb1 > 1) {
        nb1 >>= 1; nb2 >>= 1;
    }
    {
        int need = ((B + 3) / 4 + 255) / 256;
        if (nb1 > need && need > 0) nb1 = need;
        if (nb2 > need && need > 0) nb2 = need;
    }

    float* ws    = (float*)d_ws;
    float* p1    = ws;                               // nb1*32
    float* p2    = ws + (size_t)nb1 * 32;            // nb2*64
    float* w2f   = p2 + (size_t)nb2 * 64;            // 96
    float* b2f   = w2f + 96;                         // 96
    float* fw1sT = b2f + 96;                         // 512
    float* c1    = fw1sT + 512;                      // 16

    float Ninv = 1.0f / (3.0f * (float)B);

    int gridF = ((B + 1) / 2 + 255) / 256;           // 2 samples/lane
    if (gridF > 2048) gridF = 2048;

    k_stats1<<<nb1, 256, 0, stream>>>(x, w1, b1, p1, B);
    k_fin1<<<1, 256, 0, stream>>>(p1, g1, bt1, w2, b2, w2f, b2f, Ninv, nb1);
    k_stats2<<<nb2, 256, 0, stream>>>(x, w1, b1, w2f, b2f, p2, B);
    k_fin2<<<1, 256, 0, stream>>>(p2, g2, bt2, fw1, fb1, fw1sT, c1, Ninv, nb2);
    k_final<<<gridF, 256, 0, stream>>>(x, w1, b1, w2f, b2f, fw1sT, c1,
                                       fw2, fb2, (float*)d_out, B);
}

// Round 8
// 223.960 us; speedup vs baseline: 1.1350x; 1.1350x over previous
//
#include <hip/hip_runtime.h>
#include <math.h>

#define EPSV 1e-5f

// conv1 (3-tap, zero-pad) + relu at the 3 positions of one sample
__device__ __forceinline__ void conv3_relu(float x0, float x1, float x2,
                                           float wa, float wb, float wc, float bb,
                                           float& t0, float& t1, float& t2)
{
    t0 = fmaxf(fmaf(wb, x0, fmaf(wc, x1, bb)), 0.f);
    t1 = fmaxf(fmaf(wa, x0, fmaf(wb, x1, fmaf(wc, x2, bb))), 0.f);
    t2 = fmaxf(fmaf(wa, x1, fmaf(wb, x2, bb)), 0.f);
}

// ---------------------------------------------------------------------------
// Pass 1: per-channel sum/sumsq of relu(conv1(x)+b1), 16 channels.
// LDS-broadcast weights, 4 samples/lane via float4, per-lane cur[32].
// g-loop FULLY unrolled: cur[] indices must be compile-time constants or the
// array is demoted to scratch (R6: "#pragma unroll 4" -> VGPR=32, 163MB spill).
// partials[block*32 + v]: v<16 sum, v>=16 sq
// ---------------------------------------------------------------------------
__global__ __launch_bounds__(256) void k_stats1(const float* __restrict__ x,
                                                const float* __restrict__ w1,
                                                const float* __restrict__ b1,
                                                float* __restrict__ partials,
                                                int B)
{
    __shared__ float4 sW1[16];
    int t = threadIdx.x;
    if (t < 16) sW1[t] = make_float4(w1[3*t], w1[3*t+1], w1[3*t+2], b1[t]);
    __syncthreads();

    float cur[32];   // [0,16): sum, [16,32): sq
#pragma unroll
    for (int i = 0; i < 32; ++i) cur[i] = 0.f;

    int nchunk = (B + 3) >> 2;
    for (int ch = blockIdx.x * 256 + t; ch < nchunk; ch += gridDim.x * 256) {
        int s0 = ch << 2;
        float X[4][3];
        if (s0 + 4 <= B) {
            const float4* xp = (const float4*)(x + (size_t)s0 * 3);
            float4 A = xp[0], Bq = xp[1], Cq = xp[2];
            X[0][0]=A.x;  X[0][1]=A.y;  X[0][2]=A.z;
            X[1][0]=A.w;  X[1][1]=Bq.x; X[1][2]=Bq.y;
            X[2][0]=Bq.z; X[2][1]=Bq.w; X[2][2]=Cq.x;
            X[3][0]=Cq.y; X[3][1]=Cq.z; X[3][2]=Cq.w;
        } else {
#pragma unroll
            for (int m = 0; m < 4; ++m) {
                int s = s0 + m;
                if (s < B) { X[m][0]=x[3*s]; X[m][1]=x[3*s+1]; X[m][2]=x[3*s+2]; }
                else { X[m][0]=X[m][1]=X[m][2]=0.f; }
            }
        }
#pragma unroll
        for (int g = 0; g < 16; ++g) {
            float4 w = sW1[g];
#pragma unroll
            for (int m = 0; m < 4; ++m) {
                if (s0 + m < B) {
                    float t0, t1, t2;
                    conv3_relu(X[m][0], X[m][1], X[m][2], w.x, w.y, w.z, w.w, t0, t1, t2);
                    cur[g]      += t0 + t1 + t2;
                    cur[16 + g]  = fmaf(t0, t0, fmaf(t1, t1, fmaf(t2, t2, cur[16 + g])));
                }
            }
        }
    }

    // xor-tree: lane (L&31) ends holding total of slot (L&31)  [R3-proven]
    int lane = t & 63, wid = t >> 6;
#pragma unroll
    for (int i = 0; i < 32; ++i) cur[i] += __shfl_xor(cur[i], 32, 64);
#pragma unroll
    for (int half = 16; half >= 1; half >>= 1) {
#pragma unroll
        for (int i = 0; i < half; ++i) {
            bool up = (lane & half);
            float keep = up ? cur[i + half] : cur[i];
            float send = up ? cur[i] : cur[i + half];
            cur[i] = keep + __shfl_xor(send, half, 64);
        }
    }
    __shared__ float red[4][32];
    if (lane < 32) red[wid][lane] = cur[0];
    __syncthreads();
    if (t < 32)
        partials[blockIdx.x * 32 + t] = red[0][t] + red[1][t] + red[2][t] + red[3][t];
}

// ---------------------------------------------------------------------------
// Finalize 1: BN1 scale/shift, fold into conv2 weights (padding-aware bias).
// ---------------------------------------------------------------------------
__global__ __launch_bounds__(256) void k_fin1(const float* __restrict__ partials,
                                              const float* __restrict__ g1,
                                              const float* __restrict__ bt1,
                                              const float* __restrict__ w2,
                                              const float* __restrict__ b2,
                                              float* __restrict__ w2f,
                                              float* __restrict__ b2f,
                                              float Ninv, int nb)
{
    __shared__ float4 red4[32][8];
    __shared__ float tot[32];
    __shared__ float ssc[16], ssh[16];
    int t = threadIdx.x;
    {
        int v4 = t & 7, c = t >> 3;
        float4 a = make_float4(0.f, 0.f, 0.f, 0.f);
        for (int b = c; b < nb; b += 32) {
            float4 p = ((const float4*)partials)[b * 8 + v4];
            a.x += p.x; a.y += p.y; a.z += p.z; a.w += p.w;
        }
        red4[c][v4] = a;
    }
    __syncthreads();
    if (t < 8) {
        float4 a = make_float4(0.f, 0.f, 0.f, 0.f);
#pragma unroll
        for (int c = 0; c < 32; ++c) {
            float4 p = red4[c][t];
            a.x += p.x; a.y += p.y; a.z += p.z; a.w += p.w;
        }
        tot[4*t+0] = a.x; tot[4*t+1] = a.y; tot[4*t+2] = a.z; tot[4*t+3] = a.w;
    }
    __syncthreads();
    if (t < 16) {
        float mean = tot[t] * Ninv;
        float var  = fmaxf(tot[16 + t] * Ninv - mean * mean, 0.f);
        float rstd = rsqrtf(var + EPSV);
        float sc = g1[t] * rstd;
        ssc[t] = sc;
        ssh[t] = bt1[t] - mean * sc;
    }
    __syncthreads();
    if (t < 96) {
        int o = t / 3, p = t % 3;
        int g = o >> 1;
        w2f[t] = w2[t] * ssc[g];
        float wv0 = w2[3*o], wv1 = w2[3*o+1], wv2 = w2[3*o+2];
        float sv = (p == 0) ? (wv1 + wv2) : ((p == 1) ? (wv0 + wv1 + wv2) : (wv0 + wv1));
        b2f[t] = b2[o] + ssh[g] * sv;
    }
}

// ---------------------------------------------------------------------------
// Pass 2: per-channel sum/sumsq of relu(conv2(bn1(relu1))), 32 channels.
// LDS-broadcast weights, 4 samples/lane, per-lane cur[64], xor-tree tail.
// g-loop FULLY unrolled (R6 scratch-demotion lesson).
// partials[block*64 + v]: v<32 sum, v>=32 sq
// ---------------------------------------------------------------------------
__global__ __launch_bounds__(256) void k_stats2(const float* __restrict__ x,
                                                const float* __restrict__ w1,
                                                const float* __restrict__ b1,
                                                const float* __restrict__ w2f,
                                                const float* __restrict__ b2f,
                                                float* __restrict__ partials,
                                                int B)
{
    __shared__ float4 sW1[16];
    __shared__ float4 sU[32];   // ua,ub,uc,c0
    __shared__ float2 sC[32];   // c1,c2
    int t = threadIdx.x;
    if (t < 16) sW1[t] = make_float4(w1[3*t], w1[3*t+1], w1[3*t+2], b1[t]);
    else if (t >= 32 && t < 64) {
        int o = t - 32;
        sU[o] = make_float4(w2f[3*o], w2f[3*o+1], w2f[3*o+2], b2f[3*o]);
        sC[o] = make_float2(b2f[3*o+1], b2f[3*o+2]);
    }
    __syncthreads();

    float cur[64];  // [0,32): sum, [32,64): sq
#pragma unroll
    for (int i = 0; i < 64; ++i) cur[i] = 0.f;

    int nchunk = (B + 3) >> 2;
    for (int ch = blockIdx.x * 256 + t; ch < nchunk; ch += gridDim.x * 256) {
        int s0 = ch << 2;
        float X[4][3];
        if (s0 + 4 <= B) {
            const float4* xp = (const float4*)(x + (size_t)s0 * 3);
            float4 A = xp[0], Bq = xp[1], Cq = xp[2];
            X[0][0]=A.x;  X[0][1]=A.y;  X[0][2]=A.z;
            X[1][0]=A.w;  X[1][1]=Bq.x; X[1][2]=Bq.y;
            X[2][0]=Bq.z; X[2][1]=Bq.w; X[2][2]=Cq.x;
            X[3][0]=Cq.y; X[3][1]=Cq.z; X[3][2]=Cq.w;
        } else {
#pragma unroll
            for (int m = 0; m < 4; ++m) {
                int s = s0 + m;
                if (s < B) { X[m][0]=x[3*s]; X[m][1]=x[3*s+1]; X[m][2]=x[3*s+2]; }
                else { X[m][0]=X[m][1]=X[m][2]=0.f; }
            }
        }
#pragma unroll
        for (int g = 0; g < 16; ++g) {
            float4 w = sW1[g];
            float r[4][3];
#pragma unroll
            for (int m = 0; m < 4; ++m)
                conv3_relu(X[m][0], X[m][1], X[m][2], w.x, w.y, w.z, w.w,
                           r[m][0], r[m][1], r[m][2]);
#pragma unroll
            for (int jj = 0; jj < 2; ++jj) {
                int o = 2 * g + jj;
                float4 u = sU[o];
                float2 cc = sC[o];
#pragma unroll
                for (int m = 0; m < 4; ++m) {
                    if (s0 + m < B) {
                        float v0 = fmaxf(fmaf(u.y, r[m][0], fmaf(u.z, r[m][1], u.w)), 0.f);
                        float v1 = fmaxf(fmaf(u.x, r[m][0], fmaf(u.y, r[m][1], fmaf(u.z, r[m][2], cc.x))), 0.f);
                        float v2 = fmaxf(fmaf(u.x, r[m][1], fmaf(u.y, r[m][2], cc.y)), 0.f);
                        cur[o]      += v0 + v1 + v2;
                        cur[32 + o]  = fmaf(v0, v0, fmaf(v1, v1, fmaf(v2, v2, cur[32 + o])));
                    }
                }
            }
        }
    }

    // xor-tree over 64 slots: lane L ends holding total of slot L  [R3-proven]
    int lane = t & 63, wid = t >> 6;
#pragma unroll
    for (int half = 32; half >= 1; half >>= 1) {
#pragma unroll
        for (int i = 0; i < half; ++i) {
            bool up = (lane & half);
            float keep = up ? cur[i + half] : cur[i];
            float send = up ? cur[i] : cur[i + half];
            cur[i] = keep + __shfl_xor(send, half, 64);
        }
    }
    __shared__ float red[4][64];
    red[wid][lane] = cur[0];
    __syncthreads();
    if (t < 64)
        partials[blockIdx.x * 64 + t] = red[0][t] + red[1][t] + red[2][t] + red[3][t];
}

// ---------------------------------------------------------------------------
// Finalize 2: BN2 scale/shift; fold BN2 + mean(1/3) into fc1, TRANSPOSED:
// fw1sT[o*16 + j] = fw1[j*32+o] * ssc[o] / 3  (k_final reads per-channel rows)
// c1[j] = fb1[j] + sum_c fw1[j*32+c] * ssh[c]
// ---------------------------------------------------------------------------
__global__ __launch_bounds__(256) void k_fin2(const float* __restrict__ partials,
                                              const float* __restrict__ g2,
                                              const float* __restrict__ bt2,
                                              const float* __restrict__ fw1,
                                              const float* __restrict__ fb1,
                                              float* __restrict__ fw1sT,
                                              float* __restrict__ c1,
                                              float Ninv, int nb)
{
    __shared__ float4 red4[16][16];
    __shared__ float tot[64];
    __shared__ float ssc[32], ssh[32];
    int t = threadIdx.x;
    {
        int v4 = t & 15, c = t >> 4;
        float4 a = make_float4(0.f, 0.f, 0.f, 0.f);
        for (int b = c; b < nb; b += 16) {
            float4 p = ((const float4*)partials)[b * 16 + v4];
            a.x += p.x; a.y += p.y; a.z += p.z; a.w += p.w;
        }
        red4[c][v4] = a;
    }
    __syncthreads();
    if (t < 16) {
        float4 a = make_float4(0.f, 0.f, 0.f, 0.f);
#pragma unroll
        for (int c = 0; c < 16; ++c) {
            float4 p = red4[c][t];
            a.x += p.x; a.y += p.y; a.z += p.z; a.w += p.w;
        }
        tot[4*t+0] = a.x; tot[4*t+1] = a.y; tot[4*t+2] = a.z; tot[4*t+3] = a.w;
    }
    __syncthreads();
    if (t < 32) {
        float mean = tot[t] * Ninv;
        float var  = fmaxf(tot[32 + t] * Ninv - mean * mean, 0.f);
        float rstd = rsqrtf(var + EPSV);
        float sc = g2[t] * rstd;
        ssc[t] = sc;
        ssh[t] = bt2[t] - mean * sc;
    }
    __syncthreads();
    for (int idx = t; idx < 512; idx += 256) {
        int o = idx >> 4, j = idx & 15;
        fw1sT[idx] = fw1[j * 32 + o] * ssc[o] * (1.0f / 3.0f);
    }
    if (t < 16) {
        float a = fb1[t];
#pragma unroll
        for (int c = 0; c < 32; ++c) a = fmaf(fw1[t * 32 + c], ssh[c], a);
        c1[t] = a;
    }
}

// ---------------------------------------------------------------------------
// Pass 3 (R5-proven, grid 4096 = 1 sample/lane): full forward, fc1 fused into
// the conv loop; persistent state = acc[16]+x only. acc[] indices are
// constants from the fully-unrolled k-loop, so "#pragma unroll 4" on g is
// safe here (no runtime-indexed private array).
// ---------------------------------------------------------------------------
__global__ __launch_bounds__(256) void k_final(const float* __restrict__ x,
                                               const float* __restrict__ w1,
                                               const float* __restrict__ b1,
                                               const float* __restrict__ w2f,
                                               const float* __restrict__ b2f,
                                               const float* __restrict__ fw1sT,
                                               const float* __restrict__ c1,
                                               const float* __restrict__ fw2,
                                               const float* __restrict__ fb2,
                                               float* __restrict__ out,
                                               int B)
{
    __shared__ float4 sW1[16];   // conv1 w + b
    __shared__ float4 sU[32];    // conv2 w + bias(pos0)
    __shared__ float2 sC[32];    // bias(pos1), bias(pos2)
    __shared__ float4 sFT[128];  // sFT[o*4+k] = fw1sT[o*16+4k .. +3]
    __shared__ float2 sJ[16];    // (c1[j], fw2[j])
    __shared__ float  sb2;
    int t = threadIdx.x;
    if (t < 16) sW1[t] = make_float4(w1[3*t], w1[3*t+1], w1[3*t+2], b1[t]);
    else if (t >= 32 && t < 64) {
        int o = t - 32;
        sU[o] = make_float4(w2f[3*o], w2f[3*o+1], w2f[3*o+2], b2f[3*o]);
        sC[o] = make_float2(b2f[3*o+1], b2f[3*o+2]);
    } else if (t >= 64 && t < 192) {
        sFT[t - 64] = ((const float4*)fw1sT)[t - 64];
    } else if (t >= 192 && t < 208) {
        sJ[t - 192] = make_float2(c1[t - 192], fw2[t - 192]);
    } else if (t == 224) {
        sb2 = fb2[0];
    }
    __syncthreads();

    for (int s = blockIdx.x * 256 + t; s < B; s += gridDim.x * 256) {
        float x0 = x[3*s], x1 = x[3*s+1], x2 = x[3*s+2];

        float acc[16];
#pragma unroll
        for (int j = 0; j < 16; ++j) acc[j] = 0.f;

#pragma unroll 4
        for (int g = 0; g < 16; ++g) {
            float4 w = sW1[g];
            float r0, r1, r2;
            conv3_relu(x0, x1, x2, w.x, w.y, w.z, w.w, r0, r1, r2);
#pragma unroll
            for (int jj = 0; jj < 2; ++jj) {
                int o = 2 * g + jj;
                float4 u = sU[o];
                float2 cc = sC[o];
                float v0 = fmaxf(fmaf(u.y, r0, fmaf(u.z, r1, u.w)), 0.f);
                float v1 = fmaxf(fmaf(u.x, r0, fmaf(u.y, r1, fmaf(u.z, r2, cc.x))), 0.f);
                float v2 = fmaxf(fmaf(u.x, r1, fmaf(u.y, r2, cc.y)), 0.f);
                float so = v0 + v1 + v2;
#pragma unroll
                for (int k = 0; k < 4; ++k) {
                    float4 f = sFT[o * 4 + k];
                    acc[4*k+0] = fmaf(f.x, so, acc[4*k+0]);
                    acc[4*k+1] = fmaf(f.y, so, acc[4*k+1]);
                    acc[4*k+2] = fmaf(f.z, so, acc[4*k+2]);
                    acc[4*k+3] = fmaf(f.w, so, acc[4*k+3]);
                }
            }
        }

        float r = sb2;
#pragma unroll
        for (int j = 0; j < 16; ++j) {
            float2 jw = sJ[j];
            r = fmaf(jw.y, fmaxf(acc[j] + jw.x, 0.f), r);
        }
        out[s] = r;
    }
}

// ---------------------------------------------------------------------------
extern "C" void kernel_launch(void* const* d_in, const int* in_sizes, int n_in,
                              void* d_out, int out_size, void* d_ws, size_t ws_size,
                              hipStream_t stream)
{
    const float* x   = (const float*)d_in[0];
    const float* w1  = (const float*)d_in[1];
    const float* b1  = (const float*)d_in[2];
    const float* g1  = (const float*)d_in[3];
    const float* bt1 = (const float*)d_in[4];
    const float* w2  = (const float*)d_in[5];
    const float* b2  = (const float*)d_in[6];
    const float* g2  = (const float*)d_in[7];
    const float* bt2 = (const float*)d_in[8];
    const float* fw1 = (const float*)d_in[9];
    const float* fb1 = (const float*)d_in[10];
    const float* fw2 = (const float*)d_in[11];
    const float* fb2 = (const float*)d_in[12];

    int B = in_sizes[0] / 3;

    int nb1 = 1024, nb2 = 1024;
    while ((size_t)(nb1 * 32 + nb2 * 64 + 720) * sizeof(float) > ws_size && nb1 > 1) {
        nb1 >>= 1; nb2 >>= 1;
    }
    {
        int need = ((B + 3) / 4 + 255) / 256;
        if (nb1 > need && need > 0) nb1 = need;
        if (nb2 > need && need > 0) nb2 = need;
    }

    float* ws    = (float*)d_ws;
    float* p1    = ws;                               // nb1*32
    float* p2    = ws + (size_t)nb1 * 32;            // nb2*64
    float* w2f   = p2 + (size_t)nb2 * 64;            // 96
    float* b2f   = w2f + 96;                         // 96
    float* fw1sT = b2f + 96;                         // 512
    float* c1    = fw1sT + 512;                      // 16

    float Ninv = 1.0f / (3.0f * (float)B);

    int gridF = (B + 255) / 256;                     // 1 sample/lane (R5-proven)
    if (gridF > 4096) gridF = 4096;

    k_stats1<<<nb1, 256, 0, stream>>>(x, w1, b1, p1, B);
    k_fin1<<<1, 256, 0, stream>>>(p1, g1, bt1, w2, b2, w2f, b2f, Ninv, nb1);
    k_stats2<<<nb2, 256, 0, stream>>>(x, w1, b1, w2f, b2f, p2, B);
    k_fin2<<<1, 256, 0, stream>>>(p2, g2, bt2, fw1, fb1, fw1sT, c1, Ninv, nb2);
    k_final<<<gridF, 256, 0, stream>>>(x, w1, b1, w2f, b2f, fw1sT, c1,
                                       fw2, fb2, (float*)d_out, B);
}

// Round 9
// 178.360 us; speedup vs baseline: 1.4252x; 1.2557x over previous
//
#include <hip/hip_runtime.h>
#include <math.h>

#define EPSV 1e-5f

// conv1 (3-tap, zero-pad) + relu at the 3 positions of one sample
__device__ __forceinline__ void conv3_relu(float x0, float x1, float x2,
                                           float wa, float wb, float wc, float bb,
                                           float& t0, float& t1, float& t2)
{
    t0 = fmaxf(fmaf(wb, x0, fmaf(wc, x1, bb)), 0.f);
    t1 = fmaxf(fmaf(wa, x0, fmaf(wb, x1, fmaf(wc, x2, bb))), 0.f);
    t2 = fmaxf(fmaf(wa, x1, fmaf(wb, x2, bb)), 0.f);
}

// ---------------------------------------------------------------------------
// Pass 1: per-channel sum/sumsq of relu(conv1(x)+b1), 16 channels.
// Chunk-level tail predicate (R8 lesson: per-sample checks inside the
// unrolled channel loop doubled VALU issue). Grid 512: 2 iter/thread for
// load pipelining + full residency. g-loop fully unrolled (R6 lesson:
// runtime-indexed private array -> scratch).
// partials[block*32 + v]: v<16 sum, v>=16 sq
// ---------------------------------------------------------------------------
__global__ __launch_bounds__(256) void k_stats1(const float* __restrict__ x,
                                                const float* __restrict__ w1,
                                                const float* __restrict__ b1,
                                                float* __restrict__ partials,
                                                int B)
{
    __shared__ float4 sW1[16];
    int t = threadIdx.x;
    if (t < 16) sW1[t] = make_float4(w1[3*t], w1[3*t+1], w1[3*t+2], b1[t]);
    __syncthreads();

    float cur[32];   // [0,16): sum, [16,32): sq
#pragma unroll
    for (int i = 0; i < 32; ++i) cur[i] = 0.f;

    // one full sample, all 16 channels, no bounds checks
    auto accum = [&](float x0, float x1, float x2) {
#pragma unroll
        for (int g = 0; g < 16; ++g) {
            float4 w = sW1[g];
            float t0, t1, t2;
            conv3_relu(x0, x1, x2, w.x, w.y, w.z, w.w, t0, t1, t2);
            cur[g]      += t0 + t1 + t2;
            cur[16 + g]  = fmaf(t0, t0, fmaf(t1, t1, fmaf(t2, t2, cur[16 + g])));
        }
    };

    int nchunk = (B + 3) >> 2;
    for (int ch = blockIdx.x * 256 + t; ch < nchunk; ch += gridDim.x * 256) {
        int s0 = ch << 2;
        if (s0 + 4 <= B) {          // fast path: zero per-sample checks
            const float4* xp = (const float4*)(x + (size_t)s0 * 3);
            float4 A = xp[0], Bq = xp[1], Cq = xp[2];
            accum(A.x,  A.y,  A.z);
            accum(A.w,  Bq.x, Bq.y);
            accum(Bq.z, Bq.w, Cq.x);
            accum(Cq.y, Cq.z, Cq.w);
        } else {                    // cold tail (never taken when B%4==0)
            for (int m = 0; m < 4; ++m) {
                int s = s0 + m;
                if (s < B) accum(x[3*s], x[3*s+1], x[3*s+2]);
            }
        }
    }

    // xor-tree: lane (L&31) ends holding total of slot (L&31)  [R3-proven]
    int lane = t & 63, wid = t >> 6;
#pragma unroll
    for (int i = 0; i < 32; ++i) cur[i] += __shfl_xor(cur[i], 32, 64);
#pragma unroll
    for (int half = 16; half >= 1; half >>= 1) {
#pragma unroll
        for (int i = 0; i < half; ++i) {
            bool up = (lane & half);
            float keep = up ? cur[i + half] : cur[i];
            float send = up ? cur[i] : cur[i + half];
            cur[i] = keep + __shfl_xor(send, half, 64);
        }
    }
    __shared__ float red[4][32];
    if (lane < 32) red[wid][lane] = cur[0];
    __syncthreads();
    if (t < 32)
        partials[blockIdx.x * 32 + t] = red[0][t] + red[1][t] + red[2][t] + red[3][t];
}

// ---------------------------------------------------------------------------
// Finalize 1: BN1 scale/shift, fold into conv2 weights (padding-aware bias).
// ---------------------------------------------------------------------------
__global__ __launch_bounds__(256) void k_fin1(const float* __restrict__ partials,
                                              const float* __restrict__ g1,
                                              const float* __restrict__ bt1,
                                              const float* __restrict__ w2,
                                              const float* __restrict__ b2,
                                              float* __restrict__ w2f,
                                              float* __restrict__ b2f,
                                              float Ninv, int nb)
{
    __shared__ float4 red4[32][8];
    __shared__ float tot[32];
    __shared__ float ssc[16], ssh[16];
    int t = threadIdx.x;
    {
        int v4 = t & 7, c = t >> 3;
        float4 a = make_float4(0.f, 0.f, 0.f, 0.f);
        for (int b = c; b < nb; b += 32) {
            float4 p = ((const float4*)partials)[b * 8 + v4];
            a.x += p.x; a.y += p.y; a.z += p.z; a.w += p.w;
        }
        red4[c][v4] = a;
    }
    __syncthreads();
    if (t < 8) {
        float4 a = make_float4(0.f, 0.f, 0.f, 0.f);
#pragma unroll
        for (int c = 0; c < 32; ++c) {
            float4 p = red4[c][t];
            a.x += p.x; a.y += p.y; a.z += p.z; a.w += p.w;
        }
        tot[4*t+0] = a.x; tot[4*t+1] = a.y; tot[4*t+2] = a.z; tot[4*t+3] = a.w;
    }
    __syncthreads();
    if (t < 16) {
        float mean = tot[t] * Ninv;
        float var  = fmaxf(tot[16 + t] * Ninv - mean * mean, 0.f);
        float rstd = rsqrtf(var + EPSV);
        float sc = g1[t] * rstd;
        ssc[t] = sc;
        ssh[t] = bt1[t] - mean * sc;
    }
    __syncthreads();
    if (t < 96) {
        int o = t / 3, p = t % 3;
        int g = o >> 1;
        w2f[t] = w2[t] * ssc[g];
        float wv0 = w2[3*o], wv1 = w2[3*o+1], wv2 = w2[3*o+2];
        float sv = (p == 0) ? (wv1 + wv2) : ((p == 1) ? (wv0 + wv1 + wv2) : (wv0 + wv1));
        b2f[t] = b2[o] + ssh[g] * sv;
    }
}

// ---------------------------------------------------------------------------
// Pass 2: per-channel sum/sumsq of relu(conv2(bn1(relu1))), 32 channels.
// Same R9 fixes: chunk-level predicate, grid 512 (2 iter/thread, 2 blocks/CU
// resident at ~184 VGPR). g-loop fully unrolled.
// partials[block*64 + v]: v<32 sum, v>=32 sq
// ---------------------------------------------------------------------------
__global__ __launch_bounds__(256) void k_stats2(const float* __restrict__ x,
                                                const float* __restrict__ w1,
                                                const float* __restrict__ b1,
                                                const float* __restrict__ w2f,
                                                const float* __restrict__ b2f,
                                                float* __restrict__ partials,
                                                int B)
{
    __shared__ float4 sW1[16];
    __shared__ float4 sU[32];   // ua,ub,uc,c0
    __shared__ float2 sC[32];   // c1,c2
    int t = threadIdx.x;
    if (t < 16) sW1[t] = make_float4(w1[3*t], w1[3*t+1], w1[3*t+2], b1[t]);
    else if (t >= 32 && t < 64) {
        int o = t - 32;
        sU[o] = make_float4(w2f[3*o], w2f[3*o+1], w2f[3*o+2], b2f[3*o]);
        sC[o] = make_float2(b2f[3*o+1], b2f[3*o+2]);
    }
    __syncthreads();

    float cur[64];  // [0,32): sum, [32,64): sq
#pragma unroll
    for (int i = 0; i < 64; ++i) cur[i] = 0.f;

    // one full sample, all 32 channels, no bounds checks
    auto accum = [&](float x0, float x1, float x2) {
#pragma unroll
        for (int g = 0; g < 16; ++g) {
            float4 w = sW1[g];
            float r0, r1, r2;
            conv3_relu(x0, x1, x2, w.x, w.y, w.z, w.w, r0, r1, r2);
#pragma unroll
            for (int jj = 0; jj < 2; ++jj) {
                int o = 2 * g + jj;
                float4 u = sU[o];
                float2 cc = sC[o];
                float v0 = fmaxf(fmaf(u.y, r0, fmaf(u.z, r1, u.w)), 0.f);
                float v1 = fmaxf(fmaf(u.x, r0, fmaf(u.y, r1, fmaf(u.z, r2, cc.x))), 0.f);
                float v2 = fmaxf(fmaf(u.x, r1, fmaf(u.y, r2, cc.y)), 0.f);
                cur[o]      += v0 + v1 + v2;
                cur[32 + o]  = fmaf(v0, v0, fmaf(v1, v1, fmaf(v2, v2, cur[32 + o])));
            }
        }
    };

    int nchunk = (B + 3) >> 2;
    for (int ch = blockIdx.x * 256 + t; ch < nchunk; ch += gridDim.x * 256) {
        int s0 = ch << 2;
        if (s0 + 4 <= B) {          // fast path: zero per-sample checks
            const float4* xp = (const float4*)(x + (size_t)s0 * 3);
            float4 A = xp[0], Bq = xp[1], Cq = xp[2];
            accum(A.x,  A.y,  A.z);
            accum(A.w,  Bq.x, Bq.y);
            accum(Bq.z, Bq.w, Cq.x);
            accum(Cq.y, Cq.z, Cq.w);
        } else {                    // cold tail
            for (int m = 0; m < 4; ++m) {
                int s = s0 + m;
                if (s < B) accum(x[3*s], x[3*s+1], x[3*s+2]);
            }
        }
    }

    // xor-tree over 64 slots: lane L ends holding total of slot L  [R3-proven]
    int lane = t & 63, wid = t >> 6;
#pragma unroll
    for (int half = 32; half >= 1; half >>= 1) {
#pragma unroll
        for (int i = 0; i < half; ++i) {
            bool up = (lane & half);
            float keep = up ? cur[i + half] : cur[i];
            float send = up ? cur[i] : cur[i + half];
            cur[i] = keep + __shfl_xor(send, half, 64);
        }
    }
    __shared__ float red[4][64];
    red[wid][lane] = cur[0];
    __syncthreads();
    if (t < 64)
        partials[blockIdx.x * 64 + t] = red[0][t] + red[1][t] + red[2][t] + red[3][t];
}

// ---------------------------------------------------------------------------
// Finalize 2: BN2 scale/shift; fold BN2 + mean(1/3) into fc1, TRANSPOSED:
// fw1sT[o*16 + j] = fw1[j*32+o] * ssc[o] / 3  (k_final reads per-channel rows)
// c1[j] = fb1[j] + sum_c fw1[j*32+c] * ssh[c]
// ---------------------------------------------------------------------------
__global__ __launch_bounds__(256) void k_fin2(const float* __restrict__ partials,
                                              const float* __restrict__ g2,
                                              const float* __restrict__ bt2,
                                              const float* __restrict__ fw1,
                                              const float* __restrict__ fb1,
                                              float* __restrict__ fw1sT,
                                              float* __restrict__ c1,
                                              float Ninv, int nb)
{
    __shared__ float4 red4[16][16];
    __shared__ float tot[64];
    __shared__ float ssc[32], ssh[32];
    int t = threadIdx.x;
    {
        int v4 = t & 15, c = t >> 4;
        float4 a = make_float4(0.f, 0.f, 0.f, 0.f);
        for (int b = c; b < nb; b += 16) {
            float4 p = ((const float4*)partials)[b * 16 + v4];
            a.x += p.x; a.y += p.y; a.z += p.z; a.w += p.w;
        }
        red4[c][v4] = a;
    }
    __syncthreads();
    if (t < 16) {
        float4 a = make_float4(0.f, 0.f, 0.f, 0.f);
#pragma unroll
        for (int c = 0; c < 16; ++c) {
            float4 p = red4[c][t];
            a.x += p.x; a.y += p.y; a.z += p.z; a.w += p.w;
        }
        tot[4*t+0] = a.x; tot[4*t+1] = a.y; tot[4*t+2] = a.z; tot[4*t+3] = a.w;
    }
    __syncthreads();
    if (t < 32) {
        float mean = tot[t] * Ninv;
        float var  = fmaxf(tot[32 + t] * Ninv - mean * mean, 0.f);
        float rstd = rsqrtf(var + EPSV);
        float sc = g2[t] * rstd;
        ssc[t] = sc;
        ssh[t] = bt2[t] - mean * sc;
    }
    __syncthreads();
    for (int idx = t; idx < 512; idx += 256) {
        int o = idx >> 4, j = idx & 15;
        fw1sT[idx] = fw1[j * 32 + o] * ssc[o] * (1.0f / 3.0f);
    }
    if (t < 16) {
        float a = fb1[t];
#pragma unroll
        for (int c = 0; c < 32; ++c) a = fmaf(fw1[t * 32 + c], ssh[c], a);
        c1[t] = a;
    }
}

// ---------------------------------------------------------------------------
// Pass 3 (R5-proven, grid 4096 = 1 sample/lane): full forward, fc1 fused into
// the conv loop; persistent state = acc[16]+x only. acc[] indices are
// constants from the fully-unrolled k-loop, so "#pragma unroll 4" on g is
// safe here (no runtime-indexed private array).
// ---------------------------------------------------------------------------
__global__ __launch_bounds__(256) void k_final(const float* __restrict__ x,
                                               const float* __restrict__ w1,
                                               const float* __restrict__ b1,
                                               const float* __restrict__ w2f,
                                               const float* __restrict__ b2f,
                                               const float* __restrict__ fw1sT,
                                               const float* __restrict__ c1,
                                               const float* __restrict__ fw2,
                                               const float* __restrict__ fb2,
                                               float* __restrict__ out,
                                               int B)
{
    __shared__ float4 sW1[16];   // conv1 w + b
    __shared__ float4 sU[32];    // conv2 w + bias(pos0)
    __shared__ float2 sC[32];    // bias(pos1), bias(pos2)
    __shared__ float4 sFT[128];  // sFT[o*4+k] = fw1sT[o*16+4k .. +3]
    __shared__ float2 sJ[16];    // (c1[j], fw2[j])
    __shared__ float  sb2;
    int t = threadIdx.x;
    if (t < 16) sW1[t] = make_float4(w1[3*t], w1[3*t+1], w1[3*t+2], b1[t]);
    else if (t >= 32 && t < 64) {
        int o = t - 32;
        sU[o] = make_float4(w2f[3*o], w2f[3*o+1], w2f[3*o+2], b2f[3*o]);
        sC[o] = make_float2(b2f[3*o+1], b2f[3*o+2]);
    } else if (t >= 64 && t < 192) {
        sFT[t - 64] = ((const float4*)fw1sT)[t - 64];
    } else if (t >= 192 && t < 208) {
        sJ[t - 192] = make_float2(c1[t - 192], fw2[t - 192]);
    } else if (t == 224) {
        sb2 = fb2[0];
    }
    __syncthreads();

    for (int s = blockIdx.x * 256 + t; s < B; s += gridDim.x * 256) {
        float x0 = x[3*s], x1 = x[3*s+1], x2 = x[3*s+2];

        float acc[16];
#pragma unroll
        for (int j = 0; j < 16; ++j) acc[j] = 0.f;

#pragma unroll 4
        for (int g = 0; g < 16; ++g) {
            float4 w = sW1[g];
            float r0, r1, r2;
            conv3_relu(x0, x1, x2, w.x, w.y, w.z, w.w, r0, r1, r2);
#pragma unroll
            for (int jj = 0; jj < 2; ++jj) {
                int o = 2 * g + jj;
                float4 u = sU[o];
                float2 cc = sC[o];
                float v0 = fmaxf(fmaf(u.y, r0, fmaf(u.z, r1, u.w)), 0.f);
                float v1 = fmaxf(fmaf(u.x, r0, fmaf(u.y, r1, fmaf(u.z, r2, cc.x))), 0.f);
                float v2 = fmaxf(fmaf(u.x, r1, fmaf(u.y, r2, cc.y)), 0.f);
                float so = v0 + v1 + v2;
#pragma unroll
                for (int k = 0; k < 4; ++k) {
                    float4 f = sFT[o * 4 + k];
                    acc[4*k+0] = fmaf(f.x, so, acc[4*k+0]);
                    acc[4*k+1] = fmaf(f.y, so, acc[4*k+1]);
                    acc[4*k+2] = fmaf(f.z, so, acc[4*k+2]);
                    acc[4*k+3] = fmaf(f.w, so, acc[4*k+3]);
                }
            }
        }

        float r = sb2;
#pragma unroll
        for (int j = 0; j < 16; ++j) {
            float2 jw = sJ[j];
            r = fmaf(jw.y, fmaxf(acc[j] + jw.x, 0.f), r);
        }
        out[s] = r;
    }
}

// ---------------------------------------------------------------------------
extern "C" void kernel_launch(void* const* d_in, const int* in_sizes, int n_in,
                              void* d_out, int out_size, void* d_ws, size_t ws_size,
                              hipStream_t stream)
{
    const float* x   = (const float*)d_in[0];
    const float* w1  = (const float*)d_in[1];
    const float* b1  = (const float*)d_in[2];
    const float* g1  = (const float*)d_in[3];
    const float* bt1 = (const float*)d_in[4];
    const float* w2  = (const float*)d_in[5];
    const float* b2  = (const float*)d_in[6];
    const float* g2  = (const float*)d_in[7];
    const float* bt2 = (const float*)d_in[8];
    const float* fw1 = (const float*)d_in[9];
    const float* fb1 = (const float*)d_in[10];
    const float* fw2 = (const float*)d_in[11];
    const float* fb2 = (const float*)d_in[12];

    int B = in_sizes[0] / 3;

    // 512 blocks: full CU coverage with 2 blocks/CU resident at ~184 VGPR,
    // 2 chunk-iterations/thread for load pipelining (R8 lesson).
    int nb1 = 512, nb2 = 512;
    while ((size_t)(nb1 * 32 + nb2 * 64 + 720) * sizeof(float) > ws_size && nb1 > 1) {
        nb1 >>= 1; nb2 >>= 1;
    }
    {
        int need = ((B + 3) / 4 + 255) / 256;
        if (nb1 > need && need > 0) nb1 = need;
        if (nb2 > need && need > 0) nb2 = need;
    }

    float* ws    = (float*)d_ws;
    float* p1    = ws;                               // nb1*32
    float* p2    = ws + (size_t)nb1 * 32;            // nb2*64
    float* w2f   = p2 + (size_t)nb2 * 64;            // 96
    float* b2f   = w2f + 96;                         // 96
    float* fw1sT = b2f + 96;                         // 512
    float* c1    = fw1sT + 512;                      // 16

    float Ninv = 1.0f / (3.0f * (float)B);

    int gridF = (B + 255) / 256;                     // 1 sample/lane (R5-proven)
    if (gridF > 4096) gridF = 4096;

    k_stats1<<<nb1, 256, 0, stream>>>(x, w1, b1, p1, B);
    k_fin1<<<1, 256, 0, stream>>>(p1, g1, bt1, w2, b2, w2f, b2f, Ninv, nb1);
    k_stats2<<<nb2, 256, 0, stream>>>(x, w1, b1, w2f, b2f, p2, B);
    k_fin2<<<1, 256, 0, stream>>>(p2, g2, bt2, fw1, fb1, fw1sT, c1, Ninv, nb2);
    k_final<<<gridF, 256, 0, stream>>>(x, w1, b1, w2f, b2f, fw1sT, c1,
                                       fw2, fb2, (float*)d_out, B);
}

// Round 12
// 167.553 us; speedup vs baseline: 1.5171x; 1.0645x over previous
//
#include <hip/hip_runtime.h>
#include <math.h>

#define EPSV 1e-5f

// conv1 (3-tap, zero-pad) + relu at the 3 positions of one sample
__device__ __forceinline__ void conv3_relu(float x0, float x1, float x2,
                                           float wa, float wb, float wc, float bb,
                                           float& t0, float& t1, float& t2)
{
    t0 = fmaxf(fmaf(wb, x0, fmaf(wc, x1, bb)), 0.f);
    t1 = fmaxf(fmaf(wa, x0, fmaf(wb, x1, fmaf(wc, x2, bb))), 0.f);
    t2 = fmaxf(fmaf(wa, x1, fmaf(wb, x2, bb)), 0.f);
}

// ---------------------------------------------------------------------------
// Pass 1 (R9-proven): per-channel sum/sumsq of relu(conv1(x)+b1), 16 ch.
// Chunk-level tail predicate; g-loop fully unrolled (R6 lesson).
// partials[block*32 + v]: v<16 sum, v>=16 sq
// ---------------------------------------------------------------------------
__global__ __launch_bounds__(256) void k_stats1(const float* __restrict__ x,
                                                const float* __restrict__ w1,
                                                const float* __restrict__ b1,
                                                float* __restrict__ partials,
                                                int B)
{
    __shared__ float4 sW1[16];
    int t = threadIdx.x;
    if (t < 16) sW1[t] = make_float4(w1[3*t], w1[3*t+1], w1[3*t+2], b1[t]);
    __syncthreads();

    float cur[32];   // [0,16): sum, [16,32): sq
#pragma unroll
    for (int i = 0; i < 32; ++i) cur[i] = 0.f;

    auto accum = [&](float x0, float x1, float x2) {
#pragma unroll
        for (int g = 0; g < 16; ++g) {
            float4 w = sW1[g];
            float t0, t1, t2;
            conv3_relu(x0, x1, x2, w.x, w.y, w.z, w.w, t0, t1, t2);
            cur[g]      += t0 + t1 + t2;
            cur[16 + g]  = fmaf(t0, t0, fmaf(t1, t1, fmaf(t2, t2, cur[16 + g])));
        }
    };

    int nchunk = (B + 3) >> 2;
    for (int ch = blockIdx.x * 256 + t; ch < nchunk; ch += gridDim.x * 256) {
        int s0 = ch << 2;
        if (s0 + 4 <= B) {
            const float4* xp = (const float4*)(x + (size_t)s0 * 3);
            float4 A = xp[0], Bq = xp[1], Cq = xp[2];
            accum(A.x,  A.y,  A.z);
            accum(A.w,  Bq.x, Bq.y);
            accum(Bq.z, Bq.w, Cq.x);
            accum(Cq.y, Cq.z, Cq.w);
        } else {
            for (int m = 0; m < 4; ++m) {
                int s = s0 + m;
                if (s < B) accum(x[3*s], x[3*s+1], x[3*s+2]);
            }
        }
    }

    // xor-tree: lane (L&31) ends holding total of slot (L&31)  [R3-proven]
    int lane = t & 63, wid = t >> 6;
#pragma unroll
    for (int i = 0; i < 32; ++i) cur[i] += __shfl_xor(cur[i], 32, 64);
#pragma unroll
    for (int half = 16; half >= 1; half >>= 1) {
#pragma unroll
        for (int i = 0; i < half; ++i) {
            bool up = (lane & half);
            float keep = up ? cur[i + half] : cur[i];
            float send = up ? cur[i] : cur[i + half];
            cur[i] = keep + __shfl_xor(send, half, 64);
        }
    }
    __shared__ float red[4][32];
    if (lane < 32) red[wid][lane] = cur[0];
    __syncthreads();
    if (t < 32)
        partials[blockIdx.x * 32 + t] = red[0][t] + red[1][t] + red[2][t] + red[3][t];
}

// ---------------------------------------------------------------------------
// Finalize 1: BN1 scale/shift, fold into conv2 weights (padding-aware bias).
// ---------------------------------------------------------------------------
__global__ __launch_bounds__(256) void k_fin1(const float* __restrict__ partials,
                                              const float* __restrict__ g1,
                                              const float* __restrict__ bt1,
                                              const float* __restrict__ w2,
                                              const float* __restrict__ b2,
                                              float* __restrict__ w2f,
                                              float* __restrict__ b2f,
                                              float Ninv, int nb)
{
    __shared__ float4 red4[32][8];
    __shared__ float tot[32];
    __shared__ float ssc[16], ssh[16];
    int t = threadIdx.x;
    {
        int v4 = t & 7, c = t >> 3;
        float4 a = make_float4(0.f, 0.f, 0.f, 0.f);
        for (int b = c; b < nb; b += 32) {
            float4 p = ((const float4*)partials)[b * 8 + v4];
            a.x += p.x; a.y += p.y; a.z += p.z; a.w += p.w;
        }
        red4[c][v4] = a;
    }
    __syncthreads();
    if (t < 8) {
        float4 a = make_float4(0.f, 0.f, 0.f, 0.f);
#pragma unroll
        for (int c = 0; c < 32; ++c) {
            float4 p = red4[c][t];
            a.x += p.x; a.y += p.y; a.z += p.z; a.w += p.w;
        }
        tot[4*t+0] = a.x; tot[4*t+1] = a.y; tot[4*t+2] = a.z; tot[4*t+3] = a.w;
    }
    __syncthreads();
    if (t < 16) {
        float mean = tot[t] * Ninv;
        float var  = fmaxf(tot[16 + t] * Ninv - mean * mean, 0.f);
        float rstd = rsqrtf(var + EPSV);
        float sc = g1[t] * rstd;
        ssc[t] = sc;
        ssh[t] = bt1[t] - mean * sc;
    }
    __syncthreads();
    if (t < 96) {
        int o = t / 3, p = t % 3;
        int g = o >> 1;
        w2f[t] = w2[t] * ssc[g];
        float wv0 = w2[3*o], wv1 = w2[3*o+1], wv2 = w2[3*o+2];
        float sv = (p == 0) ? (wv1 + wv2) : ((p == 1) ? (wv0 + wv1 + wv2) : (wv0 + wv1));
        b2f[t] = b2[o] + ssh[g] * sv;
    }
}

// ---------------------------------------------------------------------------
// Pass 2: per-channel sum/sumsq, 32 channels, LANE-PAIR SPLIT:
// parity p=tid&1 owns conv groups [8p,8p+8) = channels [16p,16p+16).
// Per-lane cur[32] (halved vs R9's cur[64] which hit VGPR=256/8% occupancy).
// Lane pair shares one 4-sample chunk (x loads duplicated 2x, L1-served).
// Weight LDS reads are 2-address broadcasts (2-way aliasing free, m136).
// cur[] indices all compile-time constants (R6 rule); p only in LDS addrs.
// Tail: parity-preserving xor-tree (strides 2..32) -> lane L holds slot L>>1.
// partials[block*64 + v]: v<32 sum ch v, v>=32 sq ch v-32
// ---------------------------------------------------------------------------
__global__ __launch_bounds__(256) void k_stats2(const float* __restrict__ x,
                                                const float* __restrict__ w1,
                                                const float* __restrict__ b1,
                                                const float* __restrict__ w2f,
                                                const float* __restrict__ b2f,
                                                float* __restrict__ partials,
                                                int B)
{
    __shared__ float4 sW1[16];
    __shared__ float4 sU[32];   // ua,ub,uc,c0
    __shared__ float2 sC[32];   // c1,c2
    int t = threadIdx.x;
    if (t < 16) sW1[t] = make_float4(w1[3*t], w1[3*t+1], w1[3*t+2], b1[t]);
    else if (t >= 32 && t < 64) {
        int o = t - 32;
        sU[o] = make_float4(w2f[3*o], w2f[3*o+1], w2f[3*o+2], b2f[3*o]);
        sC[o] = make_float2(b2f[3*o+1], b2f[3*o+2]);
    }
    __syncthreads();

    const int p = t & 1;        // parity: which half of the channels
    const int gbase = 8 * p;    // conv groups [gbase, gbase+8)

    float cur[32];  // [0,16): sum ch 16p+i, [16,32): sq ch 16p+i
#pragma unroll
    for (int i = 0; i < 32; ++i) cur[i] = 0.f;

    // one sample, this lane's 16 channels, no bounds checks
    auto accum = [&](float x0, float x1, float x2) {
#pragma unroll
        for (int g = 0; g < 8; ++g) {
            float4 w = sW1[gbase + g];
            float r0, r1, r2;
            conv3_relu(x0, x1, x2, w.x, w.y, w.z, w.w, r0, r1, r2);
#pragma unroll
            for (int jj = 0; jj < 2; ++jj) {
                int oc = 2 * g + jj;           // 0..15, compile-time const
                int oo = 16 * p + oc;          // LDS address only
                float4 u = sU[oo];
                float2 cc = sC[oo];
                float v0 = fmaxf(fmaf(u.y, r0, fmaf(u.z, r1, u.w)), 0.f);
                float v1 = fmaxf(fmaf(u.x, r0, fmaf(u.y, r1, fmaf(u.z, r2, cc.x))), 0.f);
                float v2 = fmaxf(fmaf(u.x, r1, fmaf(u.y, r2, cc.y)), 0.f);
                cur[oc]      += v0 + v1 + v2;
                cur[16 + oc]  = fmaf(v0, v0, fmaf(v1, v1, fmaf(v2, v2, cur[16 + oc])));
            }
        }
    };

    int nchunk = (B + 3) >> 2;
    int gp     = (blockIdx.x * 256 + t) >> 1;       // global pair id
    int stride = (gridDim.x * 256) >> 1;
    for (int ch = gp; ch < nchunk; ch += stride) {
        int s0 = ch << 2;
        if (s0 + 4 <= B) {
            const float4* xp = (const float4*)(x + (size_t)s0 * 3);
            float4 A = xp[0], Bq = xp[1], Cq = xp[2];
            accum(A.x,  A.y,  A.z);
            accum(A.w,  Bq.x, Bq.y);
            accum(Bq.z, Bq.w, Cq.x);
            accum(Cq.y, Cq.z, Cq.w);
        } else {
            for (int m = 0; m < 4; ++m) {
                int s = s0 + m;
                if (s < B) accum(x[3*s], x[3*s+1], x[3*s+2]);
            }
        }
    }

    // parity-preserving xor-tree: strides 2,4,8,16,32; lane L ends with
    // slot (L>>1) of its parity's 32-slot vector.
    int lane = t & 63, wid = t >> 6;
#pragma unroll
    for (int half = 16; half >= 1; half >>= 1) {
        int d = half << 1;      // xor distance (keeps parity)
#pragma unroll
        for (int i = 0; i < half; ++i) {
            bool up = (lane & d);
            float keep = up ? cur[i + half] : cur[i];
            float send = up ? cur[i] : cur[i + half];
            cur[i] = keep + __shfl_xor(send, d, 64);
        }
    }
    // lane L: idx=L>>1 in [0,32); kind=idx>>4 (0 sum,1 sq); ch=16p+(idx&15)
    __shared__ float red[4][64];
    {
        int idx = lane >> 1;
        int v = ((idx >> 4) << 5) + 16 * p + (idx & 15);
        red[wid][v] = cur[0];
    }
    __syncthreads();
    if (t < 64)
        partials[blockIdx.x * 64 + t] = red[0][t] + red[1][t] + red[2][t] + red[3][t];
}

// ---------------------------------------------------------------------------
// Finalize 2: BN2 scale/shift; fold BN2 + mean(1/3) into fc1, TRANSPOSED:
// fw1sT[o*16 + j] = fw1[j*32+o] * ssc[o] / 3  (k_final reads per-channel rows)
// c1[j] = fb1[j] + sum_c fw1[j*32+c] * ssh[c]
// ---------------------------------------------------------------------------
__global__ __launch_bounds__(256) void k_fin2(const float* __restrict__ partials,
                                              const float* __restrict__ g2,
                                              const float* __restrict__ bt2,
                                              const float* __restrict__ fw1,
                                              const float* __restrict__ fb1,
                                              float* __restrict__ fw1sT,
                                              float* __restrict__ c1,
                                              float Ninv, int nb)
{
    __shared__ float4 red4[16][16];
    __shared__ float tot[64];
    __shared__ float ssc[32], ssh[32];
    int t = threadIdx.x;
    {
        int v4 = t & 15, c = t >> 4;
        float4 a = make_float4(0.f, 0.f, 0.f, 0.f);
        for (int b = c; b < nb; b += 16) {
            float4 p = ((const float4*)partials)[b * 16 + v4];
            a.x += p.x; a.y += p.y; a.z += p.z; a.w += p.w;
        }
        red4[c][v4] = a;
    }
    __syncthreads();
    if (t < 16) {
        float4 a = make_float4(0.f, 0.f, 0.f, 0.f);
#pragma unroll
        for (int c = 0; c < 16; ++c) {
            float4 p = red4[c][t];
            a.x += p.x; a.y += p.y; a.z += p.z; a.w += p.w;
        }
        tot[4*t+0] = a.x; tot[4*t+1] = a.y; tot[4*t+2] = a.z; tot[4*t+3] = a.w;
    }
    __syncthreads();
    if (t < 32) {
        float mean = tot[t] * Ninv;
        float var  = fmaxf(tot[32 + t] * Ninv - mean * mean, 0.f);
        float rstd = rsqrtf(var + EPSV);
        float sc = g2[t] * rstd;
        ssc[t] = sc;
        ssh[t] = bt2[t] - mean * sc;
    }
    __syncthreads();
    for (int idx = t; idx < 512; idx += 256) {
        int o = idx >> 4, j = idx & 15;
        fw1sT[idx] = fw1[j * 32 + o] * ssc[o] * (1.0f / 3.0f);
    }
    if (t < 16) {
        float a = fb1[t];
#pragma unroll
        for (int c = 0; c < 32; ++c) a = fmaf(fw1[t * 32 + c], ssh[c], a);
        c1[t] = a;
    }
}

// ---------------------------------------------------------------------------
// Pass 3 (R5-proven, grid 4096 = 1 sample/lane): full forward, fc1 fused into
// the conv loop; persistent state = acc[16]+x only.
// ---------------------------------------------------------------------------
__global__ __launch_bounds__(256) void k_final(const float* __restrict__ x,
                                               const float* __restrict__ w1,
                                               const float* __restrict__ b1,
                                               const float* __restrict__ w2f,
                                               const float* __restrict__ b2f,
                                               const float* __restrict__ fw1sT,
                                               const float* __restrict__ c1,
                                               const float* __restrict__ fw2,
                                               const float* __restrict__ fb2,
                                               float* __restrict__ out,
                                               int B)
{
    __shared__ float4 sW1[16];   // conv1 w + b
    __shared__ float4 sU[32];    // conv2 w + bias(pos0)
    __shared__ float2 sC[32];    // bias(pos1), bias(pos2)
    __shared__ float4 sFT[128];  // sFT[o*4+k] = fw1sT[o*16+4k .. +3]
    __shared__ float2 sJ[16];    // (c1[j], fw2[j])
    __shared__ float  sb2;
    int t = threadIdx.x;
    if (t < 16) sW1[t] = make_float4(w1[3*t], w1[3*t+1], w1[3*t+2], b1[t]);
    else if (t >= 32 && t < 64) {
        int o = t - 32;
        sU[o] = make_float4(w2f[3*o], w2f[3*o+1], w2f[3*o+2], b2f[3*o]);
        sC[o] = make_float2(b2f[3*o+1], b2f[3*o+2]);
    } else if (t >= 64 && t < 192) {
        sFT[t - 64] = ((const float4*)fw1sT)[t - 64];
    } else if (t >= 192 && t < 208) {
        sJ[t - 192] = make_float2(c1[t - 192], fw2[t - 192]);
    } else if (t == 224) {
        sb2 = fb2[0];
    }
    __syncthreads();

    for (int s = blockIdx.x * 256 + t; s < B; s += gridDim.x * 256) {
        float x0 = x[3*s], x1 = x[3*s+1], x2 = x[3*s+2];

        float acc[16];
#pragma unroll
        for (int j = 0; j < 16; ++j) acc[j] = 0.f;

#pragma unroll 4
        for (int g = 0; g < 16; ++g) {
            float4 w = sW1[g];
            float r0, r1, r2;
            conv3_relu(x0, x1, x2, w.x, w.y, w.z, w.w, r0, r1, r2);
#pragma unroll
            for (int jj = 0; jj < 2; ++jj) {
                int o = 2 * g + jj;
                float4 u = sU[o];
                float2 cc = sC[o];
                float v0 = fmaxf(fmaf(u.y, r0, fmaf(u.z, r1, u.w)), 0.f);
                float v1 = fmaxf(fmaf(u.x, r0, fmaf(u.y, r1, fmaf(u.z, r2, cc.x))), 0.f);
                float v2 = fmaxf(fmaf(u.x, r1, fmaf(u.y, r2, cc.y)), 0.f);
                float so = v0 + v1 + v2;
#pragma unroll
                for (int k = 0; k < 4; ++k) {
                    float4 f = sFT[o * 4 + k];
                    acc[4*k+0] = fmaf(f.x, so, acc[4*k+0]);
                    acc[4*k+1] = fmaf(f.y, so, acc[4*k+1]);
                    acc[4*k+2] = fmaf(f.z, so, acc[4*k+2]);
                    acc[4*k+3] = fmaf(f.w, so, acc[4*k+3]);
                }
            }
        }

        float r = sb2;
#pragma unroll
        for (int j = 0; j < 16; ++j) {
            float2 jw = sJ[j];
            r = fmaf(jw.y, fmaxf(acc[j] + jw.x, 0.f), r);
        }
        out[s] = r;
    }
}

// ---------------------------------------------------------------------------
extern "C" void kernel_launch(void* const* d_in, const int* in_sizes, int n_in,
                              void* d_out, int out_size, void* d_ws, size_t ws_size,
                              hipStream_t stream)
{
    const float* x   = (const float*)d_in[0];
    const float* w1  = (const float*)d_in[1];
    const float* b1  = (const float*)d_in[2];
    const float* g1  = (const float*)d_in[3];
    const float* bt1 = (const float*)d_in[4];
    const float* w2  = (const float*)d_in[5];
    const float* b2  = (const float*)d_in[6];
    const float* g2  = (const float*)d_in[7];
    const float* bt2 = (const float*)d_in[8];
    const float* fw1 = (const float*)d_in[9];
    const float* fb1 = (const float*)d_in[10];
    const float* fw2 = (const float*)d_in[11];
    const float* fb2 = (const float*)d_in[12];

    int B = in_sizes[0] / 3;

    int nb1 = 512;    // stats1: 2 blocks/CU, chunk-per-lane
    int nb2 = 1024;   // stats2: lane-pair split -> 2 chunk-iters/pair
    while ((size_t)(nb1 * 32 + nb2 * 64 + 720) * sizeof(float) > ws_size && nb1 > 1) {
        nb1 >>= 1; nb2 >>= 1;
    }

    float* ws    = (float*)d_ws;
    float* p1    = ws;                               // nb1*32
    float* p2    = ws + (size_t)nb1 * 32;            // nb2*64
    float* w2f   = p2 + (size_t)nb2 * 64;            // 96
    float* b2f   = w2f + 96;                         // 96
    float* fw1sT = b2f + 96;                         // 512
    float* c1    = fw1sT + 512;                      // 16

    float Ninv = 1.0f / (3.0f * (float)B);

    int gridF = (B + 255) / 256;                     // 1 sample/lane (R5-proven)
    if (gridF > 4096) gridF = 4096;

    k_stats1<<<nb1, 256, 0, stream>>>(x, w1, b1, p1, B);
    k_fin1<<<1, 256, 0, stream>>>(p1, g1, bt1, w2, b2, w2f, b2f, Ninv, nb1);
    k_stats2<<<nb2, 256, 0, stream>>>(x, w1, b1, w2f, b2f, p2, B);
    k_fin2<<<1, 256, 0, stream>>>(p2, g2, bt2, fw1, fb1, fw1sT, c1, Ninv, nb2);
    k_final<<<gridF, 256, 0, stream>>>(x, w1, b1, w2f, b2f, fw1sT, c1,
                                       fw2, fb2, (float*)d_out, B);
}